// Round 1
// baseline (349.042 us; speedup 1.0000x reference)
//
#include <hip/hip_runtime.h>

#define NROW 8192
#define NCOL 8192
#define RANK 256

#define BM 128
#define BN 128
#define BK 64

typedef __bf16  bf16x8 __attribute__((ext_vector_type(8)));
typedef float   f32x4  __attribute__((ext_vector_type(4)));

__device__ __forceinline__ unsigned short f2bf(float f) {
    // round-to-nearest-even fp32 -> bf16
    unsigned int u = __builtin_bit_cast(unsigned int, f);
    u += 0x7fffu + ((u >> 16) & 1u);
    return (unsigned short)(u >> 16);
}

// --- Prologue A: X (fp32, NROW x RANK) -> Xb (bf16) + x2 row norms ---
// one wave per row; lane handles 4 consecutive floats
__global__ __launch_bounds__(256) void prep_x(const float* __restrict__ X,
                                              unsigned short* __restrict__ Xb,
                                              float* __restrict__ x2) {
    const int row  = blockIdx.x * 4 + (threadIdx.x >> 6);
    const int lane = threadIdx.x & 63;
    const float4 v = ((const float4*)(X + (size_t)row * RANK))[lane];
    float s = v.x * v.x + v.y * v.y + v.z * v.z + v.w * v.w;
    ushort4 b;
    b.x = f2bf(v.x); b.y = f2bf(v.y); b.z = f2bf(v.z); b.w = f2bf(v.w);
    ((ushort4*)(Xb + (size_t)row * RANK))[lane] = b;
    #pragma unroll
    for (int off = 32; off > 0; off >>= 1) s += __shfl_down(s, off);
    if (lane == 0) x2[row] = s;
}

// --- Prologue B: Y (fp32, RANK x NCOL) -> Ybt (bf16, NCOL x RANK, transposed)
//                 + y2 column norms. Padded LDS tile transpose. ---
__global__ __launch_bounds__(256) void prep_y(const float* __restrict__ Y,
                                              unsigned short* __restrict__ Ybt,
                                              float* __restrict__ y2) {
    __shared__ float tile[64][65];   // +1 pad: conflict-free transposed reads
    __shared__ float part[256];
    const int t  = threadIdx.x;
    const int j0 = blockIdx.x * 64;
    const int tq = t >> 6;           // 0..3
    const int tl = t & 63;
    float acc = 0.f;
    for (int c = 0; c < 4; ++c) {    // k chunks of 64
        const int k0 = c * 64;
        #pragma unroll
        for (int i = 0; i < 16; ++i) {
            const int kk = tq * 16 + i;
            const float v = Y[(size_t)(k0 + kk) * NCOL + j0 + tl]; // coalesced
            tile[kk][tl] = v;
            acc += v * v;            // column j0+tl partial
        }
        __syncthreads();
        #pragma unroll
        for (int i = 0; i < 16; ++i) {
            const int jj = tq * 16 + i;
            Ybt[(size_t)(j0 + jj) * RANK + k0 + tl] = f2bf(tile[tl][jj]); // coalesced
        }
        __syncthreads();
    }
    part[t] = acc;
    __syncthreads();
    if (t < 64)
        y2[j0 + t] = part[t] + part[t + 64] + part[t + 128] + part[t + 192];
}

// --- Main: bf16 MFMA GEMM (m97 structure) + fused L2 epilogue ---
// C[m][n] = sum_k A[m][k]*Bt[n][k];  z = beta - sqrt(max(x2+y2-2C, 0))
__global__ __launch_bounds__(256, 2)
void l2_gemm(const unsigned short* __restrict__ A,   // Xb  [NROW][RANK]
             const unsigned short* __restrict__ Bt,  // Ybt [NCOL][RANK]
             const float* __restrict__ x2,
             const float* __restrict__ y2,
             const float* __restrict__ beta_p,
             float* __restrict__ out) {
    __shared__ alignas(16) unsigned short As[BM * BK];
    __shared__ alignas(16) unsigned short Bs[BN * BK];

    const int t    = threadIdx.x;
    const int wid  = t >> 6;
    const int lane = t & 63;
    const int rowBase = blockIdx.x * BM;
    const int colBase = blockIdx.y * BN;

    const int waveM = (wid >> 1) * 64;
    const int waveN = (wid & 1) * 64;

    f32x4 acc[4][4] = {};

    const int lrow = lane >> 3;        // 0..7 : row within 8-row staging chunk
    const int lcol = (lane & 7) * 8;   // 0..56: k offset (8 bf16 = 16 B)

    for (int kt = 0; kt < RANK; kt += BK) {
        // stage A tile: 128 rows x 64 k. Each wave: 4 chunks of 8 rows, 16B/lane.
        #pragma unroll
        for (int r = 0; r < 4; ++r) {
            const int rrel = r * 32 + wid * 8;
            const unsigned short* gp =
                A + (size_t)(rowBase + rrel + lrow) * RANK + kt + lcol;
            unsigned short* lp = As + rrel * BK;   // wave-uniform base; HW adds lane*16
            __builtin_amdgcn_global_load_lds(
                (__attribute__((address_space(1))) void*)gp,
                (__attribute__((address_space(3))) void*)lp, 16, 0, 0);
        }
        // stage B tile likewise
        #pragma unroll
        for (int r = 0; r < 4; ++r) {
            const int rrel = r * 32 + wid * 8;
            const unsigned short* gp =
                Bt + (size_t)(colBase + rrel + lrow) * RANK + kt + lcol;
            unsigned short* lp = Bs + rrel * BK;
            __builtin_amdgcn_global_load_lds(
                (__attribute__((address_space(1))) void*)gp,
                (__attribute__((address_space(3))) void*)lp, 16, 0, 0);
        }
        __syncthreads();

        #pragma unroll
        for (int ks = 0; ks < BK; ks += 32) {
            const int kfrag = ks + (lane >> 4) * 8;
            bf16x8 af[4], bfr[4];
            #pragma unroll
            for (int mt = 0; mt < 4; ++mt)
                af[mt] = *(const bf16x8*)(As + (waveM + mt * 16 + (lane & 15)) * BK + kfrag);
            #pragma unroll
            for (int nt = 0; nt < 4; ++nt)
                bfr[nt] = *(const bf16x8*)(Bs + (waveN + nt * 16 + (lane & 15)) * BK + kfrag);
            #pragma unroll
            for (int mt = 0; mt < 4; ++mt)
                #pragma unroll
                for (int nt = 0; nt < 4; ++nt)
                    acc[mt][nt] = __builtin_amdgcn_mfma_f32_16x16x32_bf16(
                        af[mt], bfr[nt], acc[mt][nt], 0, 0, 0);
        }
        __syncthreads();
    }

    // fused epilogue: C/D layout col = lane&15, row = (lane>>4)*4 + reg
    const float beta = *beta_p;
    const int cRow0 = rowBase + waveM + (lane >> 4) * 4;
    const int cCol0 = colBase + waveN + (lane & 15);
    #pragma unroll
    for (int nt = 0; nt < 4; ++nt) {
        const int   col = cCol0 + nt * 16;
        const float yv  = y2[col];
        #pragma unroll
        for (int mt = 0; mt < 4; ++mt) {
            #pragma unroll
            for (int r = 0; r < 4; ++r) {
                const int row = cRow0 + mt * 16 + r;
                float d2 = x2[row] + yv - 2.0f * acc[mt][nt][r];
                d2 = d2 > 0.f ? d2 : 0.f;
                out[(size_t)row * NCOL + col] = beta - sqrtf(d2);
            }
        }
    }
}

extern "C" void kernel_launch(void* const* d_in, const int* in_sizes, int n_in,
                              void* d_out, int out_size, void* d_ws, size_t ws_size,
                              hipStream_t stream) {
    const float* X    = (const float*)d_in[0];   // 8192 x 256
    const float* Y    = (const float*)d_in[1];   // 256 x 8192
    const float* beta = (const float*)d_in[2];   // scalar
    float* out = (float*)d_out;

    // workspace layout
    char* ws = (char*)d_ws;
    unsigned short* Xb  = (unsigned short*)(ws);                         // 4 MB
    unsigned short* Ybt = (unsigned short*)(ws + (size_t)4 * 1024 * 1024); // 4 MB
    float* x2 = (float*)(ws + (size_t)8 * 1024 * 1024);                  // 32 KB
    float* y2 = (float*)(ws + (size_t)8 * 1024 * 1024 + 32 * 1024);      // 32 KB

    prep_x<<<NROW / 4, 256, 0, stream>>>(X, Xb, x2);
    prep_y<<<NCOL / 64, 256, 0, stream>>>(Y, Ybt, y2);

    dim3 grid(NROW / BM, NCOL / BN);
    l2_gemm<<<grid, 256, 0, stream>>>(Xb, Ybt, x2, y2, beta, out);
}